// Round 1
// baseline (815.434 us; speedup 1.0000x reference)
//
#include <hip/hip_runtime.h>
#include <hip/hip_bf16.h>

#define IN_DIM 256
#define HC 128      // H*C = 4*32
#define H_HEADS 4
#define C_DIM 32
#define NEG_SLOPE 0.2f

// GEMM: h = x @ W  (x: [N, 256], W: [256, 128]) with fused attention dot
// products a_src[n,h] = sum_c h[n,h,c]*att_src[h*32+c], same for a_dst.
// Block: 256 threads = 2 rows x 128 cols.
__global__ void gemm_att_kernel(const float* __restrict__ x,
                                const float* __restrict__ W,
                                const float* __restrict__ att_src,
                                const float* __restrict__ att_dst,
                                float* __restrict__ h,
                                float* __restrict__ asrc,
                                float* __restrict__ adst,
                                int N) {
    __shared__ float xs[2][IN_DIM];
    const int t = threadIdx.x;
    const int lr = t >> 7;           // local row 0..1
    const int col = t & 127;
    const int r0 = blockIdx.x * 2;
    const int row = r0 + lr;

    // stage 2 rows of x (512 floats) into LDS
    for (int i = t; i < 2 * IN_DIM; i += 256) {
        int rr = i >> 8, kk = i & 255;
        xs[rr][kk] = (r0 + rr < N) ? x[(size_t)(r0 + rr) * IN_DIM + kk] : 0.f;
    }
    __syncthreads();

    float sum = 0.f;
#pragma unroll 8
    for (int k = 0; k < IN_DIM; ++k) {
        sum += xs[lr][k] * W[k * HC + col];
    }

    if (row < N) {
        h[(size_t)row * HC + col] = sum;
        float ps = sum * att_src[col];
        float pd = sum * att_dst[col];
        // reduce within each 32-lane group (one head)
#pragma unroll
        for (int m = 16; m >= 1; m >>= 1) {
            ps += __shfl_xor(ps, m);
            pd += __shfl_xor(pd, m);
        }
        if ((col & 31) == 0) {
            int head = col >> 5;
            asrc[row * H_HEADS + head] = ps;
            adst[row * H_HEADS + head] = pd;
        }
    }
}

// Edge aggregation: for each edge slot (E real edges + N self loops), each of
// 128 channel-threads computes w = exp(leakyrelu(a_src[src]+a_dst[dst])) and
// atomically accumulates w*h[src,col] into accum[dst,col]; one lane per head
// accumulates w into denom[dst,head].
__global__ void edge_agg_kernel(const int* __restrict__ ei, int E, int N,
                                const float* __restrict__ hsrc,
                                const float* __restrict__ asrc,
                                const float* __restrict__ adst,
                                float* __restrict__ accum,
                                float* __restrict__ denom) {
    const long long gid = (long long)blockIdx.x * blockDim.x + threadIdx.x;
    const long long slot = gid >> 7;
    const int col = (int)(gid & 127);
    if (slot >= (long long)(E + N)) return;

    int src, dst;
    if (slot < E) {
        src = ei[slot];
        dst = ei[E + slot];
    } else {
        src = dst = (int)(slot - E);
    }
    const int head = col >> 5;
    float alpha = asrc[src * H_HEADS + head] + adst[dst * H_HEADS + head];
    alpha = alpha > 0.f ? alpha : NEG_SLOPE * alpha;
    const float w = __expf(alpha);   // no max-shift: |alpha| small, fp32 safe

    const float val = hsrc[(size_t)src * HC + col];
    atomicAdd(accum + (size_t)dst * HC + col, w * val);
    if ((col & 31) == 0) atomicAdd(denom + dst * H_HEADS + head, w);
}

// Normalize graph-2 output in place + bias: out = accum/denom + b
__global__ void finish2_kernel(const float* __restrict__ denom,
                               const float* __restrict__ b,
                               float* __restrict__ out, int N) {
    const long long i = (long long)blockIdx.x * blockDim.x + threadIdx.x;
    if (i >= (long long)N * HC) return;
    const int n = (int)(i >> 7), col = (int)(i & 127);
    out[i] = out[i] / denom[n * H_HEADS + (col >> 5)] + b[col];
}

// Normalize graph-1 output in place + bias + gather-add x2_out[group]
__global__ void finish1_kernel(const float* __restrict__ denom,
                               const float* __restrict__ b,
                               const int* __restrict__ ga,
                               const float* __restrict__ x2out,
                               float* __restrict__ out, int N) {
    const long long i = (long long)blockIdx.x * blockDim.x + threadIdx.x;
    if (i >= (long long)N * HC) return;
    const int n = (int)(i >> 7), col = (int)(i & 127);
    float v = out[i] / denom[n * H_HEADS + (col >> 5)] + b[col];
    out[i] = v + x2out[(size_t)ga[n] * HC + col];
}

extern "C" void kernel_launch(void* const* d_in, const int* in_sizes, int n_in,
                              void* d_out, int out_size, void* d_ws, size_t ws_size,
                              hipStream_t stream) {
    const float* x1  = (const float*)d_in[0];
    const int*   ei1 = (const int*)d_in[1];
    const float* x2  = (const float*)d_in[2];
    const int*   ei2 = (const int*)d_in[3];
    const int*   ga  = (const int*)d_in[4];
    const float* W1      = (const float*)d_in[5];
    const float* attS1   = (const float*)d_in[6];
    const float* attD1   = (const float*)d_in[7];
    const float* b1      = (const float*)d_in[8];
    const float* W2      = (const float*)d_in[9];
    const float* attS2   = (const float*)d_in[10];
    const float* attD2   = (const float*)d_in[11];
    const float* b2      = (const float*)d_in[12];

    const int N1 = in_sizes[0] / IN_DIM;     // 50000
    const int E1 = in_sizes[1] / 2;          // 800000
    const int N2 = in_sizes[2] / IN_DIM;     // 10000
    const int E2 = in_sizes[3] / 2;          // 160000

    // workspace layout (floats)
    float* ws = (float*)d_ws;
    float* h1     = ws;
    float* h2     = h1 + (size_t)N1 * HC;
    float* asrc1  = h2 + (size_t)N2 * HC;
    float* adst1  = asrc1 + (size_t)N1 * H_HEADS;
    float* asrc2  = adst1 + (size_t)N1 * H_HEADS;
    float* adst2  = asrc2 + (size_t)N2 * H_HEADS;
    float* denom1 = adst2 + (size_t)N2 * H_HEADS;
    float* denom2 = denom1 + (size_t)N1 * H_HEADS;

    float* out1 = (float*)d_out;                       // x1_combined accum/result
    float* out2 = (float*)d_out + (size_t)N1 * HC;     // x2_out accum/result

    // zero accumulators (output regions + denominators)
    hipMemsetAsync(d_out, 0, (size_t)out_size * sizeof(float), stream);
    hipMemsetAsync(denom1, 0, (size_t)(N1 + N2) * H_HEADS * sizeof(float), stream);

    // GEMM + attention dots
    gemm_att_kernel<<<(N1 + 1) / 2, 256, 0, stream>>>(x1, W1, attS1, attD1,
                                                      h1, asrc1, adst1, N1);
    gemm_att_kernel<<<(N2 + 1) / 2, 256, 0, stream>>>(x2, W2, attS2, attD2,
                                                      h2, asrc2, adst2, N2);

    // edge aggregation (incl. self loops)
    {
        long long items1 = (long long)(E1 + N1) * HC;
        long long items2 = (long long)(E2 + N2) * HC;
        edge_agg_kernel<<<(int)((items1 + 255) / 256), 256, 0, stream>>>(
            ei1, E1, N1, h1, asrc1, adst1, out1, denom1);
        edge_agg_kernel<<<(int)((items2 + 255) / 256), 256, 0, stream>>>(
            ei2, E2, N2, h2, asrc2, adst2, out2, denom2);
    }

    // finish: normalize x2 first (x1 pass gathers from it)
    finish2_kernel<<<(N2 * HC + 255) / 256, 256, 0, stream>>>(denom2, b2, out2, N2);
    finish1_kernel<<<(N1 * HC + 255) / 256, 256, 0, stream>>>(denom1, b1, ga,
                                                              out2, out1, N1);
}

// Round 2
// 404.003 us; speedup vs baseline: 2.0184x; 2.0184x over previous
//
#include <hip/hip_runtime.h>
#include <hip/hip_bf16.h>

#define IN_DIM 256
#define HC 128      // H*C = 4*32
#define HH 4
#define NEG_SLOPE 0.2f
#define GR 16       // rows per gemm block

// GEMM: h = x @ W  (x: [N,256], W: [256,128]) + fused per-head attention dots.
// 128 threads = 1 col each; GR rows per block (W re-read amortized 16x).
__global__ void gemm_att_kernel(const float* __restrict__ x,
                                const float* __restrict__ W,
                                const float* __restrict__ att_src,
                                const float* __restrict__ att_dst,
                                float* __restrict__ h,
                                float* __restrict__ asrc,
                                float* __restrict__ adst,
                                int N) {
    __shared__ float xs[GR][IN_DIM];
    const int col = threadIdx.x;     // 0..127
    const int r0 = blockIdx.x * GR;

    for (int i = col; i < GR * IN_DIM; i += 128) {
        int rr = i >> 8, kk = i & 255;
        int row = r0 + rr;
        xs[rr][kk] = (row < N) ? x[(size_t)row * IN_DIM + kk] : 0.f;
    }
    __syncthreads();

    float acc[GR];
#pragma unroll
    for (int r = 0; r < GR; ++r) acc[r] = 0.f;
#pragma unroll 4
    for (int k = 0; k < IN_DIM; ++k) {
        float wv = W[k * HC + col];
#pragma unroll
        for (int r = 0; r < GR; ++r) acc[r] += xs[r][k] * wv;
    }

    const float as = att_src[col], ad = att_dst[col];
    const int head = col >> 5;
#pragma unroll
    for (int r = 0; r < GR; ++r) {
        int row = r0 + r;
        if (row >= N) break;
        h[(size_t)row * HC + col] = acc[r];
        float ps = acc[r] * as, pd = acc[r] * ad;
#pragma unroll
        for (int m = 16; m >= 1; m >>= 1) {
            ps += __shfl_xor(ps, m);
            pd += __shfl_xor(pd, m);
        }
        if ((col & 31) == 0) {
            asrc[row * HH + head] = ps;
            adst[row * HH + head] = pd;
        }
    }
}

// in-degree histogram over E real edges + N self loops
__global__ void degree_kernel(const int* __restrict__ ei, int E, int N,
                              int* __restrict__ deg) {
    int i = blockIdx.x * 256 + threadIdx.x;
    if (i < E) atomicAdd(&deg[ei[E + i]], 1);
    else if (i < E + N) atomicAdd(&deg[i - E], 1);
}

// per-256-block inclusive scan + block sums
__global__ void scan_block_kernel(const int* __restrict__ deg,
                                  int* __restrict__ incl,
                                  int* __restrict__ bsum, int n) {
    __shared__ int tmp[256];
    int t = threadIdx.x;
    int gid = blockIdx.x * 256 + t;
    tmp[t] = (gid < n) ? deg[gid] : 0;
    __syncthreads();
    for (int off = 1; off < 256; off <<= 1) {
        int v = (t >= off) ? tmp[t - off] : 0;
        __syncthreads();
        tmp[t] += v;
        __syncthreads();
    }
    if (gid < n) incl[gid] = tmp[t];
    if (t == 255) bsum[blockIdx.x] = tmp[255];
}

// single-block scan of block sums (nb <= 256)
__global__ void scan_top_kernel(int* __restrict__ data, int n) {
    __shared__ int tmp[256];
    int t = threadIdx.x;
    tmp[t] = (t < n) ? data[t] : 0;
    __syncthreads();
    for (int off = 1; off < 256; off <<= 1) {
        int v = (t >= off) ? tmp[t - off] : 0;
        __syncthreads();
        tmp[t] += v;
        __syncthreads();
    }
    if (t < n) data[t] = tmp[t];
}

__global__ void add_off_kernel(int* __restrict__ incl,
                               const int* __restrict__ bsum, int n) {
    int i = blockIdx.x * 256 + threadIdx.x;
    if (i < n && blockIdx.x > 0) incl[i] += bsum[blockIdx.x - 1];
}

// scatter edge sources into CSR buckets
__global__ void scatter_kernel(const int* __restrict__ ei, int E, int N,
                               const int* __restrict__ incl,
                               const int* __restrict__ deg,
                               int* __restrict__ cursor,
                               int* __restrict__ esrc) {
    int i = blockIdx.x * 256 + threadIdx.x;
    if (i >= E + N) return;
    int src, dst;
    if (i < E) { src = ei[i]; dst = ei[E + i]; }
    else       { src = dst = i - E; }
    int pos = incl[dst] - deg[dst] + atomicAdd(&cursor[dst], 1);
    esrc[pos] = src;
}

// gather: one 128-thread block per dst node; softmax-weighted sum over
// in-edges, normalized + bias (+ optional grouped add from `other`).
__global__ void gather_kernel(const int* __restrict__ incl,
                              const int* __restrict__ deg,
                              const int* __restrict__ esrc,
                              const float* __restrict__ h,
                              const float* __restrict__ asrc,
                              const float* __restrict__ adst,
                              const float* __restrict__ b,
                              const int* __restrict__ ga,      // nullable
                              const float* __restrict__ other, // nullable
                              float* __restrict__ out, int N) {
    const int n = blockIdx.x;
    const int col = threadIdx.x;     // 0..127
    const int head = col >> 5;
    const int d = deg[n];
    const int start = incl[n] - d;
    const float ad = adst[n * HH + head];
    float acc = 0.f, wsum = 0.f;
    for (int e = 0; e < d; ++e) {
        int src = esrc[start + e];
        float alpha = asrc[src * HH + head] + ad;
        alpha = alpha > 0.f ? alpha : NEG_SLOPE * alpha;
        float w = __expf(alpha);     // no max-shift: |alpha| small, fp32-safe
        wsum += w;                   // redundant across 32 lanes, no reduce needed
        acc += w * h[(size_t)src * HC + col];
    }
    float v = acc / wsum + b[col];
    if (ga) v += other[(size_t)ga[n] * HC + col];
    out[(size_t)n * HC + col] = v;
}

extern "C" void kernel_launch(void* const* d_in, const int* in_sizes, int n_in,
                              void* d_out, int out_size, void* d_ws, size_t ws_size,
                              hipStream_t stream) {
    const float* x1  = (const float*)d_in[0];
    const int*   ei1 = (const int*)d_in[1];
    const float* x2  = (const float*)d_in[2];
    const int*   ei2 = (const int*)d_in[3];
    const int*   ga  = (const int*)d_in[4];
    const float* W1    = (const float*)d_in[5];
    const float* attS1 = (const float*)d_in[6];
    const float* attD1 = (const float*)d_in[7];
    const float* b1    = (const float*)d_in[8];
    const float* W2    = (const float*)d_in[9];
    const float* attS2 = (const float*)d_in[10];
    const float* attD2 = (const float*)d_in[11];
    const float* b2    = (const float*)d_in[12];

    const int N1 = in_sizes[0] / IN_DIM;
    const int E1 = in_sizes[1] / 2;
    const int N2 = in_sizes[2] / IN_DIM;
    const int E2 = in_sizes[3] / 2;
    const int S1 = E1 + N1, S2 = E2 + N2;

    // ---- workspace layout ----
    char* p = (char*)d_ws;
    auto alloc = [&](size_t bytes) {
        char* r = p; p += (bytes + 511) & ~(size_t)511; return r;
    };
    float* h1    = (float*)alloc((size_t)N1 * HC * 4);
    float* h2    = (float*)alloc((size_t)N2 * HC * 4);
    float* asrc1 = (float*)alloc((size_t)N1 * HH * 4);
    float* adst1 = (float*)alloc((size_t)N1 * HH * 4);
    float* asrc2 = (float*)alloc((size_t)N2 * HH * 4);
    float* adst2 = (float*)alloc((size_t)N2 * HH * 4);
    // deg/cursor contiguous -> single memset
    int* deg1    = (int*)alloc((size_t)(N1 + N1 + N2 + N2) * 4);
    int* cursor1 = deg1 + N1;
    int* deg2    = cursor1 + N1;
    int* cursor2 = deg2 + N2;
    int* incl1   = (int*)alloc((size_t)N1 * 4);
    int* incl2   = (int*)alloc((size_t)N2 * 4);
    int* bsum1   = (int*)alloc(256 * 4);
    int* bsum2   = (int*)alloc(256 * 4);
    int* esrc1   = (int*)alloc((size_t)S1 * 4);
    int* esrc2   = (int*)alloc((size_t)S2 * 4);

    float* out1 = (float*)d_out;
    float* out2 = (float*)d_out + (size_t)N1 * HC;

    hipMemsetAsync(deg1, 0, (size_t)(2 * N1 + 2 * N2) * 4, stream);

    // GEMM + attention dots
    gemm_att_kernel<<<(N1 + GR - 1) / GR, 128, 0, stream>>>(x1, W1, attS1, attD1,
                                                            h1, asrc1, adst1, N1);
    gemm_att_kernel<<<(N2 + GR - 1) / GR, 128, 0, stream>>>(x2, W2, attS2, attD2,
                                                            h2, asrc2, adst2, N2);

    // CSR build
    degree_kernel<<<(S1 + 255) / 256, 256, 0, stream>>>(ei1, E1, N1, deg1);
    degree_kernel<<<(S2 + 255) / 256, 256, 0, stream>>>(ei2, E2, N2, deg2);

    int nb1 = (N1 + 255) / 256, nb2 = (N2 + 255) / 256;   // 196, 40 (<=256)
    scan_block_kernel<<<nb1, 256, 0, stream>>>(deg1, incl1, bsum1, N1);
    scan_block_kernel<<<nb2, 256, 0, stream>>>(deg2, incl2, bsum2, N2);
    scan_top_kernel<<<1, 256, 0, stream>>>(bsum1, nb1);
    scan_top_kernel<<<1, 256, 0, stream>>>(bsum2, nb2);
    add_off_kernel<<<nb1, 256, 0, stream>>>(incl1, bsum1, N1);
    add_off_kernel<<<nb2, 256, 0, stream>>>(incl2, bsum2, N2);

    scatter_kernel<<<(S1 + 255) / 256, 256, 0, stream>>>(ei1, E1, N1, incl1, deg1,
                                                         cursor1, esrc1);
    scatter_kernel<<<(S2 + 255) / 256, 256, 0, stream>>>(ei2, E2, N2, incl2, deg2,
                                                         cursor2, esrc2);

    // gather: graph2 first (graph1 reads out2 through ga)
    gather_kernel<<<N2, 128, 0, stream>>>(incl2, deg2, esrc2, h2, asrc2, adst2,
                                          b2, nullptr, nullptr, out2, N2);
    gather_kernel<<<N1, 128, 0, stream>>>(incl1, deg1, esrc1, h1, asrc1, adst1,
                                          b1, ga, out2, out1, N1);
}

// Round 3
// 310.725 us; speedup vs baseline: 2.6243x; 1.3002x over previous
//
#include <hip/hip_runtime.h>
#include <hip/hip_bf16.h>

#define IN_DIM 256
#define HC 128      // H*C = 4*32
#define HH 4
#define NEG_SLOPE 0.2f

typedef __attribute__((ext_vector_type(8))) short bf16x8;
typedef __attribute__((ext_vector_type(4))) float f32x4;

__device__ __forceinline__ unsigned short f2b(float f) {
    unsigned int u = __float_as_uint(f);
    u += 0x7FFFu + ((u >> 16) & 1u);          // RNE
    return (unsigned short)(u >> 16);
}
__device__ __forceinline__ float b2f(unsigned short u) {
    return __uint_as_float(((unsigned int)u) << 16);
}

// ---- prep: W -> Wt (bf16, [col][k]) and wa[k][8] = per-head W@att (src|dst) ----
__global__ void prep_kernel(const float* __restrict__ W1, const float* __restrict__ aS1,
                            const float* __restrict__ aD1,
                            const float* __restrict__ W2, const float* __restrict__ aS2,
                            const float* __restrict__ aD2,
                            unsigned short* __restrict__ Wt1, unsigned short* __restrict__ Wt2,
                            float* __restrict__ wa1, float* __restrict__ wa2) {
    const int k = threadIdx.x;   // 0..255
    {
        float s[HH] = {0, 0, 0, 0}, d[HH] = {0, 0, 0, 0};
        for (int c = 0; c < HC; ++c) {
            float w = W1[k * HC + c];
            Wt1[c * IN_DIM + k] = f2b(w);
            s[c >> 5] += w * aS1[c];
            d[c >> 5] += w * aD1[c];
        }
        for (int h = 0; h < HH; ++h) { wa1[k * 8 + h] = s[h]; wa1[k * 8 + 4 + h] = d[h]; }
    }
    {
        float s[HH] = {0, 0, 0, 0}, d[HH] = {0, 0, 0, 0};
        for (int c = 0; c < HC; ++c) {
            float w = W2[k * HC + c];
            Wt2[c * IN_DIM + k] = f2b(w);
            s[c >> 5] += w * aS2[c];
            d[c >> 5] += w * aD2[c];
        }
        for (int h = 0; h < HH; ++h) { wa2[k * 8 + h] = s[h]; wa2[k * 8 + 4 + h] = d[h]; }
    }
}

// ---- convert x -> bf16 + fused attention dots a = x @ wa ----
__global__ void convert_dots_kernel(const float* __restrict__ x,
                                    const float* __restrict__ wa,
                                    unsigned short* __restrict__ xb,
                                    float* __restrict__ asrc,
                                    float* __restrict__ adst, int N) {
    const int lane = threadIdx.x & 63;
    const int wid = threadIdx.x >> 6;
    float wreg[4][8];
#pragma unroll
    for (int i = 0; i < 4; ++i)
#pragma unroll
        for (int j = 0; j < 8; ++j) wreg[i][j] = wa[(4 * lane + i) * 8 + j];

    for (int row = blockIdx.x * 4 + wid; row < N; row += gridDim.x * 4) {
        const float4 xv = *(const float4*)(x + (size_t)row * IN_DIM + 4 * lane);
        ushort4 q;
        q.x = f2b(xv.x); q.y = f2b(xv.y); q.z = f2b(xv.z); q.w = f2b(xv.w);
        *(ushort4*)(xb + (size_t)row * IN_DIM + 4 * lane) = q;
        float xa[4] = {xv.x, xv.y, xv.z, xv.w};
        float p[8];
#pragma unroll
        for (int j = 0; j < 8; ++j) p[j] = 0.f;
#pragma unroll
        for (int i = 0; i < 4; ++i)
#pragma unroll
            for (int j = 0; j < 8; ++j) p[j] += xa[i] * wreg[i][j];
#pragma unroll
        for (int m = 32; m >= 1; m >>= 1)
#pragma unroll
            for (int j = 0; j < 8; ++j) p[j] += __shfl_xor(p[j], m);
        if (lane == 0) {
#pragma unroll
            for (int h = 0; h < HH; ++h) {
                asrc[row * HH + h] = p[h];
                adst[row * HH + h] = p[4 + h];
            }
        }
    }
}

// ---- bf16 MFMA GEMM: hb[N,128] = xb[N,256] @ W  (B from Wt[col][k]) ----
__launch_bounds__(128)
__global__ void gemm_kernel(const unsigned short* __restrict__ xb,
                            const unsigned short* __restrict__ Wt,
                            unsigned short* __restrict__ hb, int N) {
    const int lane = threadIdx.x & 63;
    const int wid = threadIdx.x >> 6;
    const int lr = lane & 15, lg = lane >> 4;
    const int r0 = blockIdx.x * 64 + wid * 32;
    int ra0 = r0 + lr;      if (ra0 > N - 1) ra0 = N - 1;
    int ra1 = r0 + 16 + lr; if (ra1 > N - 1) ra1 = N - 1;
    const unsigned short* A0 = xb + (size_t)ra0 * IN_DIM + lg * 8;
    const unsigned short* A1 = xb + (size_t)ra1 * IN_DIM + lg * 8;
    const unsigned short* B0 = Wt + (size_t)lr * IN_DIM + lg * 8;

    f32x4 acc[2][8];
#pragma unroll
    for (int h = 0; h < 2; ++h)
#pragma unroll
        for (int t = 0; t < 8; ++t) acc[h][t] = (f32x4){0.f, 0.f, 0.f, 0.f};

#pragma unroll
    for (int k0 = 0; k0 < IN_DIM; k0 += 32) {
        bf16x8 a0 = *(const bf16x8*)(A0 + k0);
        bf16x8 a1 = *(const bf16x8*)(A1 + k0);
#pragma unroll
        for (int t = 0; t < 8; ++t) {
            bf16x8 b = *(const bf16x8*)(B0 + t * 16 * IN_DIM + k0);
            acc[0][t] = __builtin_amdgcn_mfma_f32_16x16x32_bf16(a0, b, acc[0][t], 0, 0, 0);
            acc[1][t] = __builtin_amdgcn_mfma_f32_16x16x32_bf16(a1, b, acc[1][t], 0, 0, 0);
        }
    }
    // C layout: col = lane&15, row = (lane>>4)*4 + reg
#pragma unroll
    for (int half = 0; half < 2; ++half) {
        int rb = r0 + half * 16 + 4 * lg;
#pragma unroll
        for (int i = 0; i < 4; ++i) {
            int row = rb + i;
            if (row < N) {
#pragma unroll
                for (int t = 0; t < 8; ++t)
                    hb[(size_t)row * HC + t * 16 + lr] = f2b(acc[half][t][i]);
            }
        }
    }
}

// ---- CSR build (both graphs fused) ----
__global__ void degree_kernel(const int* __restrict__ ei1, int E1, int S1,
                              const int* __restrict__ ei2, int E2, int S2,
                              int* __restrict__ deg1, int* __restrict__ deg2) {
    int i = blockIdx.x * 256 + threadIdx.x;
    if (i < S1) {
        int dst = (i < E1) ? ei1[E1 + i] : i - E1;
        atomicAdd(&deg1[dst], 1);
    } else if (i < S1 + S2) {
        int k = i - S1;
        int dst = (k < E2) ? ei2[E2 + k] : k - E2;
        atomicAdd(&deg2[dst], 1);
    }
}

__global__ void scan_block_kernel(const int* __restrict__ deg1, int* __restrict__ incl1,
                                  int* __restrict__ bsum1, int n1, int nb1,
                                  const int* __restrict__ deg2, int* __restrict__ incl2,
                                  int* __restrict__ bsum2, int n2) {
    const int* deg; int* incl; int* bsum; int n, bid;
    if ((int)blockIdx.x < nb1) { deg = deg1; incl = incl1; bsum = bsum1; n = n1; bid = blockIdx.x; }
    else { deg = deg2; incl = incl2; bsum = bsum2; n = n2; bid = blockIdx.x - nb1; }
    __shared__ int tmp[256];
    int t = threadIdx.x;
    int gid = bid * 256 + t;
    tmp[t] = (gid < n) ? deg[gid] : 0;
    __syncthreads();
    for (int off = 1; off < 256; off <<= 1) {
        int v = (t >= off) ? tmp[t - off] : 0;
        __syncthreads();
        tmp[t] += v;
        __syncthreads();
    }
    if (gid < n) incl[gid] = tmp[t];
    if (t == 255) bsum[bid] = tmp[255];
}

__global__ void scan_top_kernel(int* __restrict__ b1, int n1, int* __restrict__ b2, int n2) {
    int* dd = (blockIdx.x == 0) ? b1 : b2;
    int n = (blockIdx.x == 0) ? n1 : n2;
    __shared__ int tmp[256];
    int t = threadIdx.x;
    tmp[t] = (t < n) ? dd[t] : 0;
    __syncthreads();
    for (int off = 1; off < 256; off <<= 1) {
        int v = (t >= off) ? tmp[t - off] : 0;
        __syncthreads();
        tmp[t] += v;
        __syncthreads();
    }
    if (t < n) dd[t] = tmp[t];
}

__global__ void add_off_kernel(int* __restrict__ incl1, const int* __restrict__ bsum1,
                               int n1, int nb1,
                               int* __restrict__ incl2, const int* __restrict__ bsum2, int n2) {
    int* incl; const int* bsum; int n, bid;
    if ((int)blockIdx.x < nb1) { incl = incl1; bsum = bsum1; n = n1; bid = blockIdx.x; }
    else { incl = incl2; bsum = bsum2; n = n2; bid = blockIdx.x - nb1; }
    int i = bid * 256 + threadIdx.x;
    if (i < n && bid > 0) incl[i] += bsum[bid - 1];
}

// ---- scatter + per-edge softmax weights (both graphs fused) ----
__global__ void scatter_kernel(const int* __restrict__ ei1, int E1, int S1,
                               const int* __restrict__ ei2, int E2, int S2,
                               const int* __restrict__ incl1, const int* __restrict__ deg1,
                               int* __restrict__ cur1, int* __restrict__ esrc1, float* __restrict__ w41,
                               const int* __restrict__ incl2, const int* __restrict__ deg2,
                               int* __restrict__ cur2, int* __restrict__ esrc2, float* __restrict__ w42,
                               const float* __restrict__ as1, const float* __restrict__ ad1,
                               const float* __restrict__ as2, const float* __restrict__ ad2) {
    int i = blockIdx.x * 256 + threadIdx.x;
    int src, dst;
    const int *incl, *deg; int *cur, *esrc; float* w4; const float *as, *ad;
    if (i < S1) {
        if (i < E1) { src = ei1[i]; dst = ei1[E1 + i]; } else { src = dst = i - E1; }
        incl = incl1; deg = deg1; cur = cur1; esrc = esrc1; w4 = w41; as = as1; ad = ad1;
    } else if (i < S1 + S2) {
        int k = i - S1;
        if (k < E2) { src = ei2[k]; dst = ei2[E2 + k]; } else { src = dst = k - E2; }
        incl = incl2; deg = deg2; cur = cur2; esrc = esrc2; w4 = w42; as = as2; ad = ad2;
    } else return;
    int pos = incl[dst] - deg[dst] + atomicAdd(&cur[dst], 1);
    esrc[pos] = src;
    const float4 a = *(const float4*)(as + (size_t)src * HH);
    const float4 dd = *(const float4*)(ad + (size_t)dst * HH);
    float al[4] = {a.x + dd.x, a.y + dd.y, a.z + dd.z, a.w + dd.w};
    float4 w;
    float* wp = (float*)&w;
#pragma unroll
    for (int h = 0; h < HH; ++h) {
        float v = al[h];
        v = v > 0.f ? v : NEG_SLOPE * v;
        wp[h] = __expf(v);           // no max-shift: |alpha| small, fp32-safe
    }
    *(float4*)(w4 + (size_t)pos * 4) = w;
}

// ---- gather: 32 lanes per node, bf16x4 per lane, prefetch-pipelined ----
__global__ void gather_kernel(const int* __restrict__ incl, const int* __restrict__ deg,
                              const int* __restrict__ esrc, const float* __restrict__ w4,
                              const unsigned short* __restrict__ hb,
                              const float* __restrict__ b,
                              const int* __restrict__ ga,       // nullable
                              const float* __restrict__ other,  // nullable
                              float* __restrict__ out, int N) {
    const int node = blockIdx.x * 8 + (threadIdx.x >> 5);
    if (node >= N) return;
    const int j = threadIdx.x & 31;
    const int head = j >> 3;
    const int d = deg[node];
    const int start = incl[node] - d;
    const unsigned short* hbj = hb + 4 * j;

    float4 acc = {0.f, 0.f, 0.f, 0.f};
    float wsum = 0.f;
    int s_c = esrc[start];
    float w_c = w4[(size_t)start * 4 + head];
    ushort4 h_c = *(const ushort4*)(hbj + (size_t)s_c * HC);
    for (int e = 0; e < d; ++e) {
        ushort4 hv = h_c;
        float wv = w_c;
        int en = e + 1;
        if (en < d) {
            int s = esrc[start + en];
            w_c = w4[(size_t)(start + en) * 4 + head];
            h_c = *(const ushort4*)(hbj + (size_t)s * HC);
        }
        acc.x += wv * b2f(hv.x);
        acc.y += wv * b2f(hv.y);
        acc.z += wv * b2f(hv.z);
        acc.w += wv * b2f(hv.w);
        wsum += wv;
    }
    const float inv = 1.f / wsum;
    const float4 bb = *(const float4*)(b + 4 * j);
    float4 o = {acc.x * inv + bb.x, acc.y * inv + bb.y,
                acc.z * inv + bb.z, acc.w * inv + bb.w};
    if (ga) {
        const float4 ov = *(const float4*)(other + (size_t)ga[node] * HC + 4 * j);
        o.x += ov.x; o.y += ov.y; o.z += ov.z; o.w += ov.w;
    }
    *(float4*)(out + (size_t)node * HC + 4 * j) = o;
}

extern "C" void kernel_launch(void* const* d_in, const int* in_sizes, int n_in,
                              void* d_out, int out_size, void* d_ws, size_t ws_size,
                              hipStream_t stream) {
    const float* x1  = (const float*)d_in[0];
    const int*   ei1 = (const int*)d_in[1];
    const float* x2  = (const float*)d_in[2];
    const int*   ei2 = (const int*)d_in[3];
    const int*   ga  = (const int*)d_in[4];
    const float* W1    = (const float*)d_in[5];
    const float* attS1 = (const float*)d_in[6];
    const float* attD1 = (const float*)d_in[7];
    const float* b1    = (const float*)d_in[8];
    const float* W2    = (const float*)d_in[9];
    const float* attS2 = (const float*)d_in[10];
    const float* attD2 = (const float*)d_in[11];
    const float* b2    = (const float*)d_in[12];

    const int N1 = in_sizes[0] / IN_DIM;
    const int E1 = in_sizes[1] / 2;
    const int N2 = in_sizes[2] / IN_DIM;
    const int E2 = in_sizes[3] / 2;
    const int S1 = E1 + N1, S2 = E2 + N2;

    // ---- workspace layout ----
    char* p = (char*)d_ws;
    auto alloc = [&](size_t bytes) {
        char* r = p; p += (bytes + 511) & ~(size_t)511; return r;
    };
    unsigned short* xb1 = (unsigned short*)alloc((size_t)N1 * IN_DIM * 2);
    unsigned short* xb2 = (unsigned short*)alloc((size_t)N2 * IN_DIM * 2);
    unsigned short* hb1 = (unsigned short*)alloc((size_t)N1 * HC * 2);
    unsigned short* hb2 = (unsigned short*)alloc((size_t)N2 * HC * 2);
    unsigned short* Wt1 = (unsigned short*)alloc((size_t)IN_DIM * HC * 2);
    unsigned short* Wt2 = (unsigned short*)alloc((size_t)IN_DIM * HC * 2);
    float* wa1   = (float*)alloc(IN_DIM * 8 * 4);
    float* wa2   = (float*)alloc(IN_DIM * 8 * 4);
    float* asrc1 = (float*)alloc((size_t)N1 * HH * 4);
    float* adst1 = (float*)alloc((size_t)N1 * HH * 4);
    float* asrc2 = (float*)alloc((size_t)N2 * HH * 4);
    float* adst2 = (float*)alloc((size_t)N2 * HH * 4);
    int* deg1 = (int*)alloc((size_t)(2 * N1 + 2 * N2) * 4);   // deg1|cur1|deg2|cur2
    int* cur1 = deg1 + N1;
    int* deg2 = cur1 + N1;
    int* cur2 = deg2 + N2;
    int* incl1 = (int*)alloc((size_t)N1 * 4);
    int* incl2 = (int*)alloc((size_t)N2 * 4);
    int* bsum1 = (int*)alloc(256 * 4);
    int* bsum2 = (int*)alloc(256 * 4);
    int* esrc1 = (int*)alloc((size_t)S1 * 4);
    int* esrc2 = (int*)alloc((size_t)S2 * 4);
    // w4 buffers alias xb (xb dead after gemm; scatter runs after gemm)
    float* w41 = (float*)xb1;   // S1*16B <= N1*512B
    float* w42 = (float*)xb2;

    float* out1 = (float*)d_out;
    float* out2 = (float*)d_out + (size_t)N1 * HC;

    hipMemsetAsync(deg1, 0, (size_t)(2 * N1 + 2 * N2) * 4, stream);

    prep_kernel<<<1, 256, 0, stream>>>(W1, attS1, attD1, W2, attS2, attD2,
                                       Wt1, Wt2, wa1, wa2);

    convert_dots_kernel<<<512, 256, 0, stream>>>(x1, wa1, xb1, asrc1, adst1, N1);
    convert_dots_kernel<<<128, 256, 0, stream>>>(x2, wa2, xb2, asrc2, adst2, N2);

    degree_kernel<<<(S1 + S2 + 255) / 256, 256, 0, stream>>>(ei1, E1, S1, ei2, E2, S2,
                                                             deg1, deg2);

    const int nb1 = (N1 + 255) / 256, nb2 = (N2 + 255) / 256;  // 196, 40
    scan_block_kernel<<<nb1 + nb2, 256, 0, stream>>>(deg1, incl1, bsum1, N1, nb1,
                                                     deg2, incl2, bsum2, N2);
    scan_top_kernel<<<2, 256, 0, stream>>>(bsum1, nb1, bsum2, nb2);
    add_off_kernel<<<nb1 + nb2, 256, 0, stream>>>(incl1, bsum1, N1, nb1,
                                                  incl2, bsum2, N2);

    gemm_kernel<<<(N1 + 63) / 64, 128, 0, stream>>>(xb1, Wt1, hb1, N1);
    gemm_kernel<<<(N2 + 63) / 64, 128, 0, stream>>>(xb2, Wt2, hb2, N2);

    // scatter AFTER gemms (w4 aliases xb)
    scatter_kernel<<<(S1 + S2 + 255) / 256, 256, 0, stream>>>(
        ei1, E1, S1, ei2, E2, S2,
        incl1, deg1, cur1, esrc1, w41,
        incl2, deg2, cur2, esrc2, w42,
        asrc1, adst1, asrc2, adst2);

    // gather: graph2 first (graph1 reads out2 through ga)
    gather_kernel<<<(N2 + 7) / 8, 256, 0, stream>>>(incl2, deg2, esrc2, w42, hb2,
                                                    b2, nullptr, nullptr, out2, N2);
    gather_kernel<<<(N1 + 7) / 8, 256, 0, stream>>>(incl1, deg1, esrc1, w41, hb1,
                                                    b1, ga, out2, out1, N1);
}

// Round 4
// 213.433 us; speedup vs baseline: 3.8206x; 1.4558x over previous
//
#include <hip/hip_runtime.h>
#include <hip/hip_bf16.h>

#define IN_DIM 256
#define HC 128      // H*C = 4*32
#define HH 4
#define NEG_SLOPE 0.2f

typedef __attribute__((ext_vector_type(8))) short bf16x8;
typedef __attribute__((ext_vector_type(4))) float f32x4;

__device__ __forceinline__ unsigned short f2b(float f) {
    unsigned int u = __float_as_uint(f);
    u += 0x7FFFu + ((u >> 16) & 1u);          // RNE
    return (unsigned short)(u >> 16);
}
__device__ __forceinline__ float b2f(unsigned short u) {
    return __uint_as_float(((unsigned int)u) << 16);
}

// ---- prep: W -> Wt (bf16, [col][k]) ; block 0 -> graph1, block 1 -> graph2 ----
__global__ void prep_kernel(const float* __restrict__ W1, const float* __restrict__ W2,
                            unsigned short* __restrict__ Wt1, unsigned short* __restrict__ Wt2) {
    const float* W = blockIdx.x ? W2 : W1;
    unsigned short* Wt = blockIdx.x ? Wt2 : Wt1;
    for (int idx = threadIdx.x; idx < HC * IN_DIM; idx += 256) {
        int c = idx >> 8, k = idx & 255;
        Wt[idx] = f2b(W[k * HC + c]);
    }
}

// ---- bf16 MFMA GEMM with fused fp32->bf16 A conversion ----
__launch_bounds__(128)
__global__ void gemm_kernel(const float* __restrict__ x,
                            const unsigned short* __restrict__ Wt,
                            unsigned short* __restrict__ hb, int N) {
    const int lane = threadIdx.x & 63;
    const int wid = threadIdx.x >> 6;
    const int lr = lane & 15, lg = lane >> 4;
    const int r0 = blockIdx.x * 64 + wid * 32;
    int ra0 = r0 + lr;      if (ra0 > N - 1) ra0 = N - 1;
    int ra1 = r0 + 16 + lr; if (ra1 > N - 1) ra1 = N - 1;
    const float* A0 = x + (size_t)ra0 * IN_DIM + lg * 8;
    const float* A1 = x + (size_t)ra1 * IN_DIM + lg * 8;
    const unsigned short* B0 = Wt + (size_t)lr * IN_DIM + lg * 8;

    f32x4 acc[2][8];
#pragma unroll
    for (int h = 0; h < 2; ++h)
#pragma unroll
        for (int t = 0; t < 8; ++t) acc[h][t] = (f32x4){0.f, 0.f, 0.f, 0.f};

#pragma unroll
    for (int k0 = 0; k0 < IN_DIM; k0 += 32) {
        float4 a0l = *(const float4*)(A0 + k0);
        float4 a0h = *(const float4*)(A0 + k0 + 4);
        float4 a1l = *(const float4*)(A1 + k0);
        float4 a1h = *(const float4*)(A1 + k0 + 4);
        bf16x8 a0, a1;
        a0[0] = f2b(a0l.x); a0[1] = f2b(a0l.y); a0[2] = f2b(a0l.z); a0[3] = f2b(a0l.w);
        a0[4] = f2b(a0h.x); a0[5] = f2b(a0h.y); a0[6] = f2b(a0h.z); a0[7] = f2b(a0h.w);
        a1[0] = f2b(a1l.x); a1[1] = f2b(a1l.y); a1[2] = f2b(a1l.z); a1[3] = f2b(a1l.w);
        a1[4] = f2b(a1h.x); a1[5] = f2b(a1h.y); a1[6] = f2b(a1h.z); a1[7] = f2b(a1h.w);
#pragma unroll
        for (int t = 0; t < 8; ++t) {
            bf16x8 b = *(const bf16x8*)(B0 + t * 16 * IN_DIM + k0);
            acc[0][t] = __builtin_amdgcn_mfma_f32_16x16x32_bf16(a0, b, acc[0][t], 0, 0, 0);
            acc[1][t] = __builtin_amdgcn_mfma_f32_16x16x32_bf16(a1, b, acc[1][t], 0, 0, 0);
        }
    }
    // C layout: col = lane&15, row = (lane>>4)*4 + reg
#pragma unroll
    for (int half = 0; half < 2; ++half) {
        int rb = r0 + half * 16 + 4 * lg;
#pragma unroll
        for (int i = 0; i < 4; ++i) {
            int row = rb + i;
            if (row < N) {
#pragma unroll
                for (int t = 0; t < 8; ++t)
                    hb[(size_t)row * HC + t * 16 + lr] = f2b(acc[half][t][i]);
            }
        }
    }
}

// ---- attention dots from hb: a_src[n,h] = sum_c hb[n,h*32+c]*attS[h*32+c] ----
__global__ void dots_kernel(const unsigned short* __restrict__ hb,
                            const float* __restrict__ attS,
                            const float* __restrict__ attD,
                            float* __restrict__ asrc, float* __restrict__ adst, int N) {
    const int row = blockIdx.x * 4 + (threadIdx.x >> 6);
    if (row >= N) return;
    const int l = threadIdx.x & 63;           // lane covers cols 2l, 2l+1
    ushort2 hv = *(const ushort2*)(hb + (size_t)row * HC + 2 * l);
    float h0 = b2f(hv.x), h1 = b2f(hv.y);
    float s = h0 * attS[2 * l] + h1 * attS[2 * l + 1];
    float d = h0 * attD[2 * l] + h1 * attD[2 * l + 1];
#pragma unroll
    for (int m = 8; m >= 1; m >>= 1) {        // reduce within 16-lane head group
        s += __shfl_xor(s, m);
        d += __shfl_xor(d, m);
    }
    if ((l & 15) == 0) {
        int head = l >> 4;
        asrc[row * HH + head] = s;
        adst[row * HH + head] = d;
    }
}

// ---- degree + rank (both graphs fused): rank[i] = arrival order at dst ----
__global__ void degree_rank_kernel(const int* __restrict__ ei1, int E1, int S1,
                                   const int* __restrict__ ei2, int E2, int S2,
                                   int* __restrict__ deg1, int* __restrict__ deg2,
                                   int* __restrict__ rank) {
    int i = blockIdx.x * 256 + threadIdx.x;
    if (i < S1) {
        int dst = (i < E1) ? ei1[E1 + i] : i - E1;
        rank[i] = atomicAdd(&deg1[dst], 1);
    } else if (i < S1 + S2) {
        int k = i - S1;
        int dst = (k < E2) ? ei2[E2 + k] : k - E2;
        rank[i] = atomicAdd(&deg2[dst], 1);
    }
}

__global__ void scan_block_kernel(const int* __restrict__ deg1, int* __restrict__ incl1,
                                  int* __restrict__ bsum1, int n1, int nb1,
                                  const int* __restrict__ deg2, int* __restrict__ incl2,
                                  int* __restrict__ bsum2, int n2) {
    const int* deg; int* incl; int* bsum; int n, bid;
    if ((int)blockIdx.x < nb1) { deg = deg1; incl = incl1; bsum = bsum1; n = n1; bid = blockIdx.x; }
    else { deg = deg2; incl = incl2; bsum = bsum2; n = n2; bid = blockIdx.x - nb1; }
    __shared__ int tmp[256];
    int t = threadIdx.x;
    int gid = bid * 256 + t;
    tmp[t] = (gid < n) ? deg[gid] : 0;
    __syncthreads();
    for (int off = 1; off < 256; off <<= 1) {
        int v = (t >= off) ? tmp[t - off] : 0;
        __syncthreads();
        tmp[t] += v;
        __syncthreads();
    }
    if (gid < n) incl[gid] = tmp[t];
    if (t == 255) bsum[bid] = tmp[255];
}

__global__ void scan_top_kernel(int* __restrict__ b1, int n1, int* __restrict__ b2, int n2) {
    int* dd = (blockIdx.x == 0) ? b1 : b2;
    int n = (blockIdx.x == 0) ? n1 : n2;
    __shared__ int tmp[256];
    int t = threadIdx.x;
    tmp[t] = (t < n) ? dd[t] : 0;
    __syncthreads();
    for (int off = 1; off < 256; off <<= 1) {
        int v = (t >= off) ? tmp[t - off] : 0;
        __syncthreads();
        tmp[t] += v;
        __syncthreads();
    }
    if (t < n) dd[t] = tmp[t];
}

// excl[i] = global exclusive scan = incl + blockoffset - deg
__global__ void add_off_kernel(const int* __restrict__ incl1, const int* __restrict__ bsum1,
                               const int* __restrict__ deg1, int* __restrict__ excl1,
                               int n1, int nb1,
                               const int* __restrict__ incl2, const int* __restrict__ bsum2,
                               const int* __restrict__ deg2, int* __restrict__ excl2, int n2) {
    const int *incl, *bsum, *deg; int* excl; int n, bid;
    if ((int)blockIdx.x < nb1) { incl = incl1; bsum = bsum1; deg = deg1; excl = excl1; n = n1; bid = blockIdx.x; }
    else { incl = incl2; bsum = bsum2; deg = deg2; excl = excl2; n = n2; bid = blockIdx.x - nb1; }
    int i = bid * 256 + threadIdx.x;
    if (i < n) excl[i] = incl[i] + (bid > 0 ? bsum[bid - 1] : 0) - deg[i];
}

// ---- scatter (atomic-free): pos = excl[dst] + rank[i] ----
__global__ void scatter_kernel(const int* __restrict__ ei1, int E1, int S1,
                               const int* __restrict__ ei2, int E2, int S2,
                               const int* __restrict__ excl1, int* __restrict__ esrc1,
                               const int* __restrict__ excl2, int* __restrict__ esrc2,
                               const int* __restrict__ rank) {
    int i = blockIdx.x * 256 + threadIdx.x;
    if (i < S1) {
        int src, dst;
        if (i < E1) { src = ei1[i]; dst = ei1[E1 + i]; } else { src = dst = i - E1; }
        esrc1[excl1[dst] + rank[i]] = src;
    } else if (i < S1 + S2) {
        int k = i - S1, src, dst;
        if (k < E2) { src = ei2[k]; dst = ei2[E2 + k]; } else { src = dst = k - E2; }
        esrc2[excl2[dst] + rank[i]] = src;
    }
}

// ---- gather: 32 lanes/node, weights recomputed from asrc/adst, 2-deep prefetch ----
__global__ void gather_kernel(const int* __restrict__ excl, const int* __restrict__ deg,
                              const int* __restrict__ esrc,
                              const float* __restrict__ asrc, const float* __restrict__ adst,
                              const unsigned short* __restrict__ hb,
                              const float* __restrict__ b,
                              const int* __restrict__ ga,       // nullable
                              const float* __restrict__ other,  // nullable
                              float* __restrict__ out, int N) {
    const int node = blockIdx.x * 8 + (threadIdx.x >> 5);
    if (node >= N) return;
    const int j = threadIdx.x & 31;
    const int head = j >> 3;
    const int d = deg[node];
    const int start = excl[node];
    const float ad = adst[node * HH + head];
    const unsigned short* hbj = hb + 4 * j;

    float4 acc = {0.f, 0.f, 0.f, 0.f};
    float wsum = 0.f;
    int s0 = esrc[start];
    int s1 = (d > 1) ? esrc[start + 1] : 0;
    float a_c = asrc[s0 * HH + head];
    ushort4 h_c = *(const ushort4*)(hbj + (size_t)s0 * HC);
    for (int e = 0; e < d; ++e) {
        float av = a_c;
        ushort4 hv = h_c;
        int s2 = (e + 2 < d) ? esrc[start + e + 2] : 0;
        if (e + 1 < d) {
            a_c = asrc[s1 * HH + head];
            h_c = *(const ushort4*)(hbj + (size_t)s1 * HC);
        }
        float alpha = av + ad;
        alpha = alpha > 0.f ? alpha : NEG_SLOPE * alpha;
        float w = __expf(alpha);     // no max-shift: |alpha| small, fp32-safe
        acc.x += w * b2f(hv.x);
        acc.y += w * b2f(hv.y);
        acc.z += w * b2f(hv.z);
        acc.w += w * b2f(hv.w);
        wsum += w;
        s0 = s1; s1 = s2;
    }
    const float inv = 1.f / wsum;
    const float4 bb = *(const float4*)(b + 4 * j);
    float4 o = {acc.x * inv + bb.x, acc.y * inv + bb.y,
                acc.z * inv + bb.z, acc.w * inv + bb.w};
    if (ga) {
        const float4 ov = *(const float4*)(other + (size_t)ga[node] * HC + 4 * j);
        o.x += ov.x; o.y += ov.y; o.z += ov.z; o.w += ov.w;
    }
    *(float4*)(out + (size_t)node * HC + 4 * j) = o;
}

extern "C" void kernel_launch(void* const* d_in, const int* in_sizes, int n_in,
                              void* d_out, int out_size, void* d_ws, size_t ws_size,
                              hipStream_t stream) {
    const float* x1  = (const float*)d_in[0];
    const int*   ei1 = (const int*)d_in[1];
    const float* x2  = (const float*)d_in[2];
    const int*   ei2 = (const int*)d_in[3];
    const int*   ga  = (const int*)d_in[4];
    const float* W1    = (const float*)d_in[5];
    const float* attS1 = (const float*)d_in[6];
    const float* attD1 = (const float*)d_in[7];
    const float* b1    = (const float*)d_in[8];
    const float* W2    = (const float*)d_in[9];
    const float* attS2 = (const float*)d_in[10];
    const float* attD2 = (const float*)d_in[11];
    const float* b2    = (const float*)d_in[12];

    const int N1 = in_sizes[0] / IN_DIM;
    const int E1 = in_sizes[1] / 2;
    const int N2 = in_sizes[2] / IN_DIM;
    const int E2 = in_sizes[3] / 2;
    const int S1 = E1 + N1, S2 = E2 + N2;

    // ---- workspace layout ----
    char* p = (char*)d_ws;
    auto alloc = [&](size_t bytes) {
        char* r = p; p += (bytes + 511) & ~(size_t)511; return r;
    };
    unsigned short* hb1 = (unsigned short*)alloc((size_t)N1 * HC * 2);
    unsigned short* hb2 = (unsigned short*)alloc((size_t)N2 * HC * 2);
    unsigned short* Wt1 = (unsigned short*)alloc((size_t)IN_DIM * HC * 2);
    unsigned short* Wt2 = (unsigned short*)alloc((size_t)IN_DIM * HC * 2);
    float* asrc1 = (float*)alloc((size_t)N1 * HH * 4);
    float* adst1 = (float*)alloc((size_t)N1 * HH * 4);
    float* asrc2 = (float*)alloc((size_t)N2 * HH * 4);
    float* adst2 = (float*)alloc((size_t)N2 * HH * 4);
    int* deg1 = (int*)alloc((size_t)(N1 + N2) * 4);   // deg1|deg2 -> one memset
    int* deg2 = deg1 + N1;
    int* incl1 = (int*)alloc((size_t)N1 * 4);
    int* incl2 = (int*)alloc((size_t)N2 * 4);
    int* excl1 = (int*)alloc((size_t)N1 * 4);
    int* excl2 = (int*)alloc((size_t)N2 * 4);
    int* bsum1 = (int*)alloc(256 * 4);
    int* bsum2 = (int*)alloc(256 * 4);
    int* rank  = (int*)alloc((size_t)(S1 + S2) * 4);
    int* esrc1 = (int*)alloc((size_t)S1 * 4);
    int* esrc2 = (int*)alloc((size_t)S2 * 4);

    float* out1 = (float*)d_out;
    float* out2 = (float*)d_out + (size_t)N1 * HC;

    hipMemsetAsync(deg1, 0, (size_t)(N1 + N2) * 4, stream);

    prep_kernel<<<2, 256, 0, stream>>>(W1, W2, Wt1, Wt2);

    degree_rank_kernel<<<(S1 + S2 + 255) / 256, 256, 0, stream>>>(
        ei1, E1, S1, ei2, E2, S2, deg1, deg2, rank);

    const int nb1 = (N1 + 255) / 256, nb2 = (N2 + 255) / 256;  // 196, 40
    scan_block_kernel<<<nb1 + nb2, 256, 0, stream>>>(deg1, incl1, bsum1, N1, nb1,
                                                     deg2, incl2, bsum2, N2);
    scan_top_kernel<<<2, 256, 0, stream>>>(bsum1, nb1, bsum2, nb2);
    add_off_kernel<<<nb1 + nb2, 256, 0, stream>>>(incl1, bsum1, deg1, excl1, N1, nb1,
                                                  incl2, bsum2, deg2, excl2, N2);

    gemm_kernel<<<(N1 + 63) / 64, 128, 0, stream>>>(x1, Wt1, hb1, N1);
    gemm_kernel<<<(N2 + 63) / 64, 128, 0, stream>>>(x2, Wt2, hb2, N2);

    dots_kernel<<<(N1 + 3) / 4, 256, 0, stream>>>(hb1, attS1, attD1, asrc1, adst1, N1);
    dots_kernel<<<(N2 + 3) / 4, 256, 0, stream>>>(hb2, attS2, attD2, asrc2, adst2, N2);

    scatter_kernel<<<(S1 + S2 + 255) / 256, 256, 0, stream>>>(
        ei1, E1, S1, ei2, E2, S2, excl1, esrc1, excl2, esrc2, rank);

    // gather: graph2 first (graph1 reads out2 through ga)
    gather_kernel<<<(N2 + 7) / 8, 256, 0, stream>>>(excl2, deg2, esrc2, asrc2, adst2,
                                                    hb2, b2, nullptr, nullptr, out2, N2);
    gather_kernel<<<(N1 + 7) / 8, 256, 0, stream>>>(excl1, deg1, esrc1, asrc1, adst1,
                                                    hb1, b1, ga, out2, out1, N1);
}

// Round 5
// 196.222 us; speedup vs baseline: 4.1557x; 1.0877x over previous
//
#include <hip/hip_runtime.h>
#include <hip/hip_bf16.h>

#define IN_DIM 256
#define HC 128      // H*C = 4*32
#define HH 4
#define NEG_SLOPE 0.2f

typedef __attribute__((ext_vector_type(8))) short bf16x8;
typedef __attribute__((ext_vector_type(4))) float f32x4;

__device__ __forceinline__ unsigned short f2b(float f) {
    unsigned int u = __float_as_uint(f);
    u += 0x7FFFu + ((u >> 16) & 1u);          // RNE
    return (unsigned short)(u >> 16);
}
__device__ __forceinline__ float b2f(unsigned short u) {
    return __uint_as_float(((unsigned int)u) << 16);
}

// ---- prep: W -> Wt (bf16, [col][k]) ; block 0 -> graph1, block 1 -> graph2 ----
__global__ void prep_kernel(const float* __restrict__ W1, const float* __restrict__ W2,
                            unsigned short* __restrict__ Wt1, unsigned short* __restrict__ Wt2) {
    const float* W = blockIdx.x ? W2 : W1;
    unsigned short* Wt = blockIdx.x ? Wt2 : Wt1;
    for (int idx = threadIdx.x; idx < HC * IN_DIM; idx += 256) {
        int c = idx >> 8, k = idx & 255;
        Wt[idx] = f2b(W[k * HC + c]);
    }
}

// ---- bf16 MFMA GEMM (fp32 A converted in-register) + fused attention dots ----
__launch_bounds__(128)
__global__ void gemm_kernel(const float* __restrict__ x,
                            const unsigned short* __restrict__ Wt,
                            const float* __restrict__ attS,
                            const float* __restrict__ attD,
                            unsigned short* __restrict__ hb,
                            float* __restrict__ asrc,
                            float* __restrict__ adst, int N) {
    const int lane = threadIdx.x & 63;
    const int wid = threadIdx.x >> 6;
    const int lr = lane & 15, lg = lane >> 4;
    const int r0 = blockIdx.x * 64 + wid * 32;
    int ra0 = r0 + lr;      if (ra0 > N - 1) ra0 = N - 1;
    int ra1 = r0 + 16 + lr; if (ra1 > N - 1) ra1 = N - 1;
    const float* A0 = x + (size_t)ra0 * IN_DIM + lg * 8;
    const float* A1 = x + (size_t)ra1 * IN_DIM + lg * 8;
    const unsigned short* B0 = Wt + (size_t)lr * IN_DIM + lg * 8;

    f32x4 acc[2][8];
#pragma unroll
    for (int h = 0; h < 2; ++h)
#pragma unroll
        for (int t = 0; t < 8; ++t) acc[h][t] = (f32x4){0.f, 0.f, 0.f, 0.f};

#pragma unroll
    for (int k0 = 0; k0 < IN_DIM; k0 += 32) {
        float4 a0l = *(const float4*)(A0 + k0);
        float4 a0h = *(const float4*)(A0 + k0 + 4);
        float4 a1l = *(const float4*)(A1 + k0);
        float4 a1h = *(const float4*)(A1 + k0 + 4);
        bf16x8 a0, a1;
        a0[0] = f2b(a0l.x); a0[1] = f2b(a0l.y); a0[2] = f2b(a0l.z); a0[3] = f2b(a0l.w);
        a0[4] = f2b(a0h.x); a0[5] = f2b(a0h.y); a0[6] = f2b(a0h.z); a0[7] = f2b(a0h.w);
        a1[0] = f2b(a1l.x); a1[1] = f2b(a1l.y); a1[2] = f2b(a1l.z); a1[3] = f2b(a1l.w);
        a1[4] = f2b(a1h.x); a1[5] = f2b(a1h.y); a1[6] = f2b(a1h.z); a1[7] = f2b(a1h.w);
#pragma unroll
        for (int t = 0; t < 8; ++t) {
            bf16x8 b = *(const bf16x8*)(B0 + t * 16 * IN_DIM + k0);
            acc[0][t] = __builtin_amdgcn_mfma_f32_16x16x32_bf16(a0, b, acc[0][t], 0, 0, 0);
            acc[1][t] = __builtin_amdgcn_mfma_f32_16x16x32_bf16(a1, b, acc[1][t], 0, 0, 0);
        }
    }

    // preload att vectors for this lane's column slice
    float attS_r[8], attD_r[8];
#pragma unroll
    for (int t = 0; t < 8; ++t) {
        attS_r[t] = attS[t * 16 + lr];
        attD_r[t] = attD[t * 16 + lr];
    }

    // C layout: col = t*16 + (lane&15), row = r0 + half*16 + 4*(lane>>4) + i
#pragma unroll
    for (int half = 0; half < 2; ++half) {
#pragma unroll
        for (int i = 0; i < 4; ++i) {
            int row = r0 + half * 16 + 4 * lg + i;
            // fused dots: per-head partial over this lane's 8 cols
            float s[4] = {0.f, 0.f, 0.f, 0.f}, dd[4] = {0.f, 0.f, 0.f, 0.f};
#pragma unroll
            for (int t = 0; t < 8; ++t) {
                float c = acc[half][t][i];
                s[t >> 1] += c * attS_r[t];
                dd[t >> 1] += c * attD_r[t];
            }
#pragma unroll
            for (int m = 1; m < 16; m <<= 1) {
#pragma unroll
                for (int h = 0; h < 4; ++h) {
                    s[h] += __shfl_xor(s[h], m);
                    dd[h] += __shfl_xor(dd[h], m);
                }
            }
            if (row < N) {
#pragma unroll
                for (int t = 0; t < 8; ++t)
                    hb[(size_t)row * HC + t * 16 + lr] = f2b(acc[half][t][i]);
                if (lr == 0) {
#pragma unroll
                    for (int h = 0; h < 4; ++h) {
                        asrc[row * HH + h] = s[h];
                        adst[row * HH + h] = dd[h];
                    }
                }
            }
        }
    }
}

// ---- degree + rank (both graphs fused): rank[i] = arrival order at dst ----
__global__ void degree_rank_kernel(const int* __restrict__ ei1, int E1, int S1,
                                   const int* __restrict__ ei2, int E2, int S2,
                                   int* __restrict__ deg1, int* __restrict__ deg2,
                                   int* __restrict__ rank) {
    int i = blockIdx.x * 256 + threadIdx.x;
    if (i < S1) {
        int dst = (i < E1) ? ei1[E1 + i] : i - E1;
        rank[i] = atomicAdd(&deg1[dst], 1);
    } else if (i < S1 + S2) {
        int k = i - S1;
        int dst = (k < E2) ? ei2[E2 + k] : k - E2;
        rank[i] = atomicAdd(&deg2[dst], 1);
    }
}

__global__ void scan_block_kernel(const int* __restrict__ deg1, int* __restrict__ incl1,
                                  int* __restrict__ bsum1, int n1, int nb1,
                                  const int* __restrict__ deg2, int* __restrict__ incl2,
                                  int* __restrict__ bsum2, int n2) {
    const int* deg; int* incl; int* bsum; int n, bid;
    if ((int)blockIdx.x < nb1) { deg = deg1; incl = incl1; bsum = bsum1; n = n1; bid = blockIdx.x; }
    else { deg = deg2; incl = incl2; bsum = bsum2; n = n2; bid = blockIdx.x - nb1; }
    __shared__ int tmp[256];
    int t = threadIdx.x;
    int gid = bid * 256 + t;
    tmp[t] = (gid < n) ? deg[gid] : 0;
    __syncthreads();
    for (int off = 1; off < 256; off <<= 1) {
        int v = (t >= off) ? tmp[t - off] : 0;
        __syncthreads();
        tmp[t] += v;
        __syncthreads();
    }
    if (gid < n) incl[gid] = tmp[t];
    if (t == 255) bsum[bid] = tmp[255];
}

__global__ void scan_top_kernel(int* __restrict__ b1, int n1, int* __restrict__ b2, int n2) {
    int* dd = (blockIdx.x == 0) ? b1 : b2;
    int n = (blockIdx.x == 0) ? n1 : n2;
    __shared__ int tmp[256];
    int t = threadIdx.x;
    tmp[t] = (t < n) ? dd[t] : 0;
    __syncthreads();
    for (int off = 1; off < 256; off <<= 1) {
        int v = (t >= off) ? tmp[t - off] : 0;
        __syncthreads();
        tmp[t] += v;
        __syncthreads();
    }
    if (t < n) dd[t] = tmp[t];
}

// excl[i] = global exclusive scan = incl + blockoffset - deg
__global__ void add_off_kernel(const int* __restrict__ incl1, const int* __restrict__ bsum1,
                               const int* __restrict__ deg1, int* __restrict__ excl1,
                               int n1, int nb1,
                               const int* __restrict__ incl2, const int* __restrict__ bsum2,
                               const int* __restrict__ deg2, int* __restrict__ excl2, int n2) {
    const int *incl, *bsum, *deg; int* excl; int n, bid;
    if ((int)blockIdx.x < nb1) { incl = incl1; bsum = bsum1; deg = deg1; excl = excl1; n = n1; bid = blockIdx.x; }
    else { incl = incl2; bsum = bsum2; deg = deg2; excl = excl2; n = n2; bid = blockIdx.x - nb1; }
    int i = bid * 256 + threadIdx.x;
    if (i < n) excl[i] = incl[i] + (bid > 0 ? bsum[bid - 1] : 0) - deg[i];
}

// ---- scatter (atomic-free): record {src, pad, w_bf16[4]} at excl[dst]+rank ----
__global__ void scatter_kernel(const int* __restrict__ ei1, int E1, int S1,
                               const int* __restrict__ ei2, int E2, int S2,
                               const int* __restrict__ excl1, int4* __restrict__ esw1,
                               const int* __restrict__ excl2, int4* __restrict__ esw2,
                               const int* __restrict__ rank,
                               const float* __restrict__ as1, const float* __restrict__ ad1,
                               const float* __restrict__ as2, const float* __restrict__ ad2) {
    int i = blockIdx.x * 256 + threadIdx.x;
    int src, dst;
    const int* excl; int4* esw; const float *as, *ad;
    if (i < S1) {
        if (i < E1) { src = ei1[i]; dst = ei1[E1 + i]; } else { src = dst = i - E1; }
        excl = excl1; esw = esw1; as = as1; ad = ad1;
    } else if (i < S1 + S2) {
        int k = i - S1;
        if (k < E2) { src = ei2[k]; dst = ei2[E2 + k]; } else { src = dst = k - E2; }
        excl = excl2; esw = esw2; as = as2; ad = ad2;
    } else return;
    int pos = excl[dst] + rank[i];
    const float4 a = *(const float4*)(as + (size_t)src * HH);
    const float4 dv = *(const float4*)(ad + (size_t)dst * HH);
    float al[4] = {a.x + dv.x, a.y + dv.y, a.z + dv.z, a.w + dv.w};
    unsigned short wb[4];
#pragma unroll
    for (int h = 0; h < HH; ++h) {
        float v = al[h];
        v = v > 0.f ? v : NEG_SLOPE * v;
        wb[h] = f2b(__expf(v));      // no max-shift: |alpha| small, fp32-safe
    }
    int4 rec;
    rec.x = src;
    rec.y = 0;
    rec.z = (int)((unsigned)wb[0] | ((unsigned)wb[1] << 16));
    rec.w = (int)((unsigned)wb[2] | ((unsigned)wb[3] << 16));
    esw[pos] = rec;
}

// ---- gather: 32 lanes/node, 4-edge groups, depth-2 pipeline ----
__global__ void gather_kernel(const int* __restrict__ excl, const int* __restrict__ deg,
                              const int4* __restrict__ esw,
                              const unsigned short* __restrict__ hb,
                              const float* __restrict__ b,
                              const int* __restrict__ ga,       // nullable
                              const float* __restrict__ other,  // nullable
                              float* __restrict__ out, int N) {
    const int node = blockIdx.x * 8 + (threadIdx.x >> 5);
    if (node >= N) return;
    const int j = threadIdx.x & 31;
    const int head = j >> 3;
    const int d = deg[node];
    const int start = excl[node];
    const unsigned short* hbj = hb + 4 * j;

    float4 acc = {0.f, 0.f, 0.f, 0.f};
    float wsum = 0.f;

    int4 rC[4], rN[4];
    ushort4 hC[4];
    // prologue: group0 records+data, group1 records (pad makes all loads safe)
#pragma unroll
    for (int k = 0; k < 4; ++k) rC[k] = esw[start + k];
#pragma unroll
    for (int k = 0; k < 4; ++k)
        hC[k] = *(const ushort4*)(hbj + (size_t)rC[k].x * HC);
#pragma unroll
    for (int k = 0; k < 4; ++k) rN[k] = esw[start + 4 + k];

    for (int e = 0; e < d; e += 4) {
        // compute edges e..e+3
#pragma unroll
        for (int k = 0; k < 4; ++k) {
            unsigned int pk = (head < 2) ? (unsigned)rC[k].z : (unsigned)rC[k].w;
            unsigned short wu = (head & 1) ? (unsigned short)(pk >> 16)
                                           : (unsigned short)(pk & 0xffff);
            float w = (e + k < d) ? b2f(wu) : 0.f;
            acc.x += w * b2f(hC[k].x);
            acc.y += w * b2f(hC[k].y);
            acc.z += w * b2f(hC[k].z);
            acc.w += w * b2f(hC[k].w);
            wsum += w;
        }
        // rotate + prefetch next groups
#pragma unroll
        for (int k = 0; k < 4; ++k) rC[k] = rN[k];
#pragma unroll
        for (int k = 0; k < 4; ++k)
            hC[k] = *(const ushort4*)(hbj + (size_t)rC[k].x * HC);
#pragma unroll
        for (int k = 0; k < 4; ++k) rN[k] = esw[start + e + 8 + k];
    }

    const float inv = 1.f / wsum;
    const float4 bb = *(const float4*)(b + 4 * j);
    float4 o = {acc.x * inv + bb.x, acc.y * inv + bb.y,
                acc.z * inv + bb.z, acc.w * inv + bb.w};
    if (ga) {
        const float4 ov = *(const float4*)(other + (size_t)ga[node] * HC + 4 * j);
        o.x += ov.x; o.y += ov.y; o.z += ov.z; o.w += ov.w;
    }
    *(float4*)(out + (size_t)node * HC + 4 * j) = o;
}

extern "C" void kernel_launch(void* const* d_in, const int* in_sizes, int n_in,
                              void* d_out, int out_size, void* d_ws, size_t ws_size,
                              hipStream_t stream) {
    const float* x1  = (const float*)d_in[0];
    const int*   ei1 = (const int*)d_in[1];
    const float* x2  = (const float*)d_in[2];
    const int*   ei2 = (const int*)d_in[3];
    const int*   ga  = (const int*)d_in[4];
    const float* W1    = (const float*)d_in[5];
    const float* attS1 = (const float*)d_in[6];
    const float* attD1 = (const float*)d_in[7];
    const float* b1    = (const float*)d_in[8];
    const float* W2    = (const float*)d_in[9];
    const float* attS2 = (const float*)d_in[10];
    const float* attD2 = (const float*)d_in[11];
    const float* b2    = (const float*)d_in[12];

    const int N1 = in_sizes[0] / IN_DIM;
    const int E1 = in_sizes[1] / 2;
    const int N2 = in_sizes[2] / IN_DIM;
    const int E2 = in_sizes[3] / 2;
    const int S1 = E1 + N1, S2 = E2 + N2;

    // ---- workspace layout ----
    char* p = (char*)d_ws;
    auto alloc = [&](size_t bytes) {
        char* r = p; p += (bytes + 511) & ~(size_t)511; return r;
    };
    unsigned short* hb1 = (unsigned short*)alloc((size_t)N1 * HC * 2);
    unsigned short* hb2 = (unsigned short*)alloc((size_t)N2 * HC * 2);
    unsigned short* Wt1 = (unsigned short*)alloc((size_t)IN_DIM * HC * 2);
    unsigned short* Wt2 = (unsigned short*)alloc((size_t)IN_DIM * HC * 2);
    float* asrc1 = (float*)alloc((size_t)N1 * HH * 4);
    float* adst1 = (float*)alloc((size_t)N1 * HH * 4);
    float* asrc2 = (float*)alloc((size_t)N2 * HH * 4);
    float* adst2 = (float*)alloc((size_t)N2 * HH * 4);
    int* deg1 = (int*)alloc((size_t)(N1 + N2) * 4);   // deg1|deg2 -> one memset
    int* deg2 = deg1 + N1;
    int* incl1 = (int*)alloc((size_t)N1 * 4);
    int* incl2 = (int*)alloc((size_t)N2 * 4);
    int* excl1 = (int*)alloc((size_t)N1 * 4);
    int* excl2 = (int*)alloc((size_t)N2 * 4);
    int* bsum1 = (int*)alloc(256 * 4);
    int* bsum2 = (int*)alloc(256 * 4);
    int* rank  = (int*)alloc((size_t)(S1 + S2) * 4);
    int4* esw1 = (int4*)alloc((size_t)(S1 + 16) * 16);
    int4* esw2 = (int4*)alloc((size_t)(S2 + 16) * 16);

    float* out1 = (float*)d_out;
    float* out2 = (float*)d_out + (size_t)N1 * HC;

    hipMemsetAsync(deg1, 0, (size_t)(N1 + N2) * 4, stream);
    hipMemsetAsync(esw1 + S1, 0, 16 * 16, stream);   // zero prefetch pad
    hipMemsetAsync(esw2 + S2, 0, 16 * 16, stream);

    prep_kernel<<<2, 256, 0, stream>>>(W1, W2, Wt1, Wt2);

    degree_rank_kernel<<<(S1 + S2 + 255) / 256, 256, 0, stream>>>(
        ei1, E1, S1, ei2, E2, S2, deg1, deg2, rank);

    const int nb1 = (N1 + 255) / 256, nb2 = (N2 + 255) / 256;  // 196, 40
    scan_block_kernel<<<nb1 + nb2, 256, 0, stream>>>(deg1, incl1, bsum1, N1, nb1,
                                                     deg2, incl2, bsum2, N2);
    scan_top_kernel<<<2, 256, 0, stream>>>(bsum1, nb1, bsum2, nb2);
    add_off_kernel<<<nb1 + nb2, 256, 0, stream>>>(incl1, bsum1, deg1, excl1, N1, nb1,
                                                  incl2, bsum2, deg2, excl2, N2);

    gemm_kernel<<<(N1 + 63) / 64, 128, 0, stream>>>(x1, Wt1, attS1, attD1,
                                                    hb1, asrc1, adst1, N1);
    gemm_kernel<<<(N2 + 63) / 64, 128, 0, stream>>>(x2, Wt2, attS2, attD2,
                                                    hb2, asrc2, adst2, N2);

    scatter_kernel<<<(S1 + S2 + 255) / 256, 256, 0, stream>>>(
        ei1, E1, S1, ei2, E2, S2, excl1, esw1, excl2, esw2, rank,
        asrc1, adst1, asrc2, adst2);

    // gather: graph2 first (graph1 reads out2 through ga)
    gather_kernel<<<(N2 + 7) / 8, 256, 0, stream>>>(excl2, deg2, esw2, hb2,
                                                    b2, nullptr, nullptr, out2, N2);
    gather_kernel<<<(N1 + 7) / 8, 256, 0, stream>>>(excl1, deg1, esw1, hb1,
                                                    b1, ga, out2, out1, N1);
}

// Round 6
// 170.253 us; speedup vs baseline: 4.7895x; 1.1525x over previous
//
#include <hip/hip_runtime.h>
#include <hip/hip_bf16.h>

#define IN_DIM 256
#define HC 128      // H*C = 4*32
#define HH 4
#define NEG_SLOPE 0.2f

typedef __attribute__((ext_vector_type(8))) short bf16x8;
typedef __attribute__((ext_vector_type(4))) float f32x4;

__device__ __forceinline__ unsigned short f2b(float f) {
    unsigned int u = __float_as_uint(f);
    u += 0x7FFFu + ((u >> 16) & 1u);          // RNE
    return (unsigned short)(u >> 16);
}
__device__ __forceinline__ float b2f(unsigned short u) {
    return __uint_as_float(((unsigned int)u) << 16);
}

// ---- prep: W -> Wt (bf16, [col][k]) ; block 0 -> graph1, block 1 -> graph2 ----
__global__ void prep_kernel(const float* __restrict__ W1, const float* __restrict__ W2,
                            unsigned short* __restrict__ Wt1, unsigned short* __restrict__ Wt2) {
    const float* W = blockIdx.x ? W2 : W1;
    unsigned short* Wt = blockIdx.x ? Wt2 : Wt1;
    for (int idx = threadIdx.x; idx < HC * IN_DIM; idx += 256) {
        int c = idx >> 8, k = idx & 255;
        Wt[idx] = f2b(W[k * HC + c]);
    }
}

// ---- gemm body: 256 threads = 4 waves, 32 rows each (128 rows/block) ----
__device__ __forceinline__ void gemm_body(int blk, int tid,
                                          const float* __restrict__ x,
                                          const unsigned short* __restrict__ Wt,
                                          const float* __restrict__ attS,
                                          const float* __restrict__ attD,
                                          unsigned short* __restrict__ hb,
                                          float* __restrict__ asrc,
                                          float* __restrict__ adst, int N) {
    const int lane = tid & 63;
    const int wid = tid >> 6;                 // 0..3
    const int lr = lane & 15, lg = lane >> 4;
    const int r0 = blk * 128 + wid * 32;
    if (r0 >= N + 31) { /* fully out of range only if r0 >= N; still guard below */ }
    int ra0 = r0 + lr;      if (ra0 > N - 1) ra0 = N - 1;
    int ra1 = r0 + 16 + lr; if (ra1 > N - 1) ra1 = N - 1;
    const float* A0 = x + (size_t)ra0 * IN_DIM + lg * 8;
    const float* A1 = x + (size_t)ra1 * IN_DIM + lg * 8;
    const unsigned short* B0 = Wt + (size_t)lr * IN_DIM + lg * 8;

    f32x4 acc[2][8];
#pragma unroll
    for (int h = 0; h < 2; ++h)
#pragma unroll
        for (int t = 0; t < 8; ++t) acc[h][t] = (f32x4){0.f, 0.f, 0.f, 0.f};

#pragma unroll
    for (int k0 = 0; k0 < IN_DIM; k0 += 32) {
        float4 a0l = *(const float4*)(A0 + k0);
        float4 a0h = *(const float4*)(A0 + k0 + 4);
        float4 a1l = *(const float4*)(A1 + k0);
        float4 a1h = *(const float4*)(A1 + k0 + 4);
        bf16x8 a0, a1;
        a0[0] = f2b(a0l.x); a0[1] = f2b(a0l.y); a0[2] = f2b(a0l.z); a0[3] = f2b(a0l.w);
        a0[4] = f2b(a0h.x); a0[5] = f2b(a0h.y); a0[6] = f2b(a0h.z); a0[7] = f2b(a0h.w);
        a1[0] = f2b(a1l.x); a1[1] = f2b(a1l.y); a1[2] = f2b(a1l.z); a1[3] = f2b(a1l.w);
        a1[4] = f2b(a1h.x); a1[5] = f2b(a1h.y); a1[6] = f2b(a1h.z); a1[7] = f2b(a1h.w);
#pragma unroll
        for (int t = 0; t < 8; ++t) {
            bf16x8 b = *(const bf16x8*)(B0 + t * 16 * IN_DIM + k0);
            acc[0][t] = __builtin_amdgcn_mfma_f32_16x16x32_bf16(a0, b, acc[0][t], 0, 0, 0);
            acc[1][t] = __builtin_amdgcn_mfma_f32_16x16x32_bf16(a1, b, acc[1][t], 0, 0, 0);
        }
    }

    float attS_r[8], attD_r[8];
#pragma unroll
    for (int t = 0; t < 8; ++t) {
        attS_r[t] = attS[t * 16 + lr];
        attD_r[t] = attD[t * 16 + lr];
    }

    // C layout: col = t*16 + (lane&15), row = r0 + half*16 + 4*(lane>>4) + i
#pragma unroll
    for (int half = 0; half < 2; ++half) {
#pragma unroll
        for (int i = 0; i < 4; ++i) {
            int row = r0 + half * 16 + 4 * lg + i;
            float s[4] = {0.f, 0.f, 0.f, 0.f}, dd[4] = {0.f, 0.f, 0.f, 0.f};
#pragma unroll
            for (int t = 0; t < 8; ++t) {
                float c = acc[half][t][i];
                s[t >> 1] += c * attS_r[t];
                dd[t >> 1] += c * attD_r[t];
            }
#pragma unroll
            for (int m = 1; m < 16; m <<= 1) {
#pragma unroll
                for (int h = 0; h < 4; ++h) {
                    s[h] += __shfl_xor(s[h], m);
                    dd[h] += __shfl_xor(dd[h], m);
                }
            }
            if (row < N) {
#pragma unroll
                for (int t = 0; t < 8; ++t)
                    hb[(size_t)row * HC + t * 16 + lr] = f2b(acc[half][t][i]);
                if (lr == 0) {
#pragma unroll
                    for (int h = 0; h < 4; ++h) {
                        asrc[row * HH + h] = s[h];
                        adst[row * HH + h] = dd[h];
                    }
                }
            }
        }
    }
}

// ---- degree body: 4 edges per thread (ILP over the memory-side atomic unit) ----
__device__ __forceinline__ void degree_body(int blk, int tid,
                                            const int* __restrict__ ei1, int E1, int S1,
                                            const int* __restrict__ ei2, int E2, int S2,
                                            int* __restrict__ deg1, int* __restrict__ deg2,
                                            int* __restrict__ rank) {
    const int base = blk * 1024 + tid;
#pragma unroll
    for (int k = 0; k < 4; ++k) {
        int i = base + k * 256;
        if (i < S1) {
            int dst = (i < E1) ? ei1[E1 + i] : i - E1;
            rank[i] = atomicAdd(&deg1[dst], 1);
        } else if (i < S1 + S2) {
            int q = i - S1;
            int dst = (q < E2) ? ei2[E2 + q] : q - E2;
            rank[i] = atomicAdd(&deg2[dst], 1);
        }
    }
}

// ---- MEGA1: gemm1 | gemm2 | degree_rank, grid-sectioned (independent work) ----
__launch_bounds__(256)
__global__ void mega1_kernel(const float* __restrict__ x1,
                             const unsigned short* __restrict__ Wt1,
                             const float* __restrict__ attS1, const float* __restrict__ attD1,
                             unsigned short* __restrict__ hb1,
                             float* __restrict__ asrc1, float* __restrict__ adst1, int N1,
                             const float* __restrict__ x2,
                             const unsigned short* __restrict__ Wt2,
                             const float* __restrict__ attS2, const float* __restrict__ attD2,
                             unsigned short* __restrict__ hb2,
                             float* __restrict__ asrc2, float* __restrict__ adst2, int N2,
                             const int* __restrict__ ei1, int E1, int S1,
                             const int* __restrict__ ei2, int E2, int S2,
                             int* __restrict__ deg1, int* __restrict__ deg2,
                             int* __restrict__ rank,
                             int G1, int G2) {
    const int b = blockIdx.x;
    const int tid = threadIdx.x;
    if (b < G1) {
        gemm_body(b, tid, x1, Wt1, attS1, attD1, hb1, asrc1, adst1, N1);
    } else if (b < G1 + G2) {
        gemm_body(b - G1, tid, x2, Wt2, attS2, attD2, hb2, asrc2, adst2, N2);
    } else {
        degree_body(b - G1 - G2, tid, ei1, E1, S1, ei2, E2, S2, deg1, deg2, rank);
    }
}

__global__ void scan_block_kernel(const int* __restrict__ deg1, int* __restrict__ incl1,
                                  int* __restrict__ bsum1, int n1, int nb1,
                                  const int* __restrict__ deg2, int* __restrict__ incl2,
                                  int* __restrict__ bsum2, int n2) {
    const int* deg; int* incl; int* bsum; int n, bid;
    if ((int)blockIdx.x < nb1) { deg = deg1; incl = incl1; bsum = bsum1; n = n1; bid = blockIdx.x; }
    else { deg = deg2; incl = incl2; bsum = bsum2; n = n2; bid = blockIdx.x - nb1; }
    __shared__ int tmp[256];
    int t = threadIdx.x;
    int gid = bid * 256 + t;
    tmp[t] = (gid < n) ? deg[gid] : 0;
    __syncthreads();
    for (int off = 1; off < 256; off <<= 1) {
        int v = (t >= off) ? tmp[t - off] : 0;
        __syncthreads();
        tmp[t] += v;
        __syncthreads();
    }
    if (gid < n) incl[gid] = tmp[t];
    if (t == 255) bsum[bid] = tmp[255];
}

__global__ void scan_top_kernel(int* __restrict__ b1, int n1, int* __restrict__ b2, int n2) {
    int* dd = (blockIdx.x == 0) ? b1 : b2;
    int n = (blockIdx.x == 0) ? n1 : n2;
    __shared__ int tmp[256];
    int t = threadIdx.x;
    tmp[t] = (t < n) ? dd[t] : 0;
    __syncthreads();
    for (int off = 1; off < 256; off <<= 1) {
        int v = (t >= off) ? tmp[t - off] : 0;
        __syncthreads();
        tmp[t] += v;
        __syncthreads();
    }
    if (t < n) dd[t] = tmp[t];
}

// excl[i] = global exclusive scan = incl + blockoffset - deg
__global__ void add_off_kernel(const int* __restrict__ incl1, const int* __restrict__ bsum1,
                               const int* __restrict__ deg1, int* __restrict__ excl1,
                               int n1, int nb1,
                               const int* __restrict__ incl2, const int* __restrict__ bsum2,
                               const int* __restrict__ deg2, int* __restrict__ excl2, int n2) {
    const int *incl, *bsum, *deg; int* excl; int n, bid;
    if ((int)blockIdx.x < nb1) { incl = incl1; bsum = bsum1; deg = deg1; excl = excl1; n = n1; bid = blockIdx.x; }
    else { incl = incl2; bsum = bsum2; deg = deg2; excl = excl2; n = n2; bid = blockIdx.x - nb1; }
    int i = bid * 256 + threadIdx.x;
    if (i < n) excl[i] = incl[i] + (bid > 0 ? bsum[bid - 1] : 0) - deg[i];
}

// ---- scatter (atomic-free): record {src, pad, w_bf16[4]} at excl[dst]+rank ----
__global__ void scatter_kernel(const int* __restrict__ ei1, int E1, int S1,
                               const int* __restrict__ ei2, int E2, int S2,
                               const int* __restrict__ excl1, int4* __restrict__ esw1,
                               const int* __restrict__ excl2, int4* __restrict__ esw2,
                               const int* __restrict__ rank,
                               const float* __restrict__ as1, const float* __restrict__ ad1,
                               const float* __restrict__ as2, const float* __restrict__ ad2) {
    int i = blockIdx.x * 256 + threadIdx.x;
    int src, dst;
    const int* excl; int4* esw; const float *as, *ad;
    if (i < S1) {
        if (i < E1) { src = ei1[i]; dst = ei1[E1 + i]; } else { src = dst = i - E1; }
        excl = excl1; esw = esw1; as = as1; ad = ad1;
    } else if (i < S1 + S2) {
        int k = i - S1;
        if (k < E2) { src = ei2[k]; dst = ei2[E2 + k]; } else { src = dst = k - E2; }
        excl = excl2; esw = esw2; as = as2; ad = ad2;
    } else return;
    int pos = excl[dst] + rank[i];
    const float4 a = *(const float4*)(as + (size_t)src * HH);
    const float4 dv = *(const float4*)(ad + (size_t)dst * HH);
    float al[4] = {a.x + dv.x, a.y + dv.y, a.z + dv.z, a.w + dv.w};
    unsigned short wb[4];
#pragma unroll
    for (int h = 0; h < HH; ++h) {
        float v = al[h];
        v = v > 0.f ? v : NEG_SLOPE * v;
        wb[h] = f2b(__expf(v));      // no max-shift: |alpha| small, fp32-safe
    }
    int4 rec;
    rec.x = src;
    rec.y = 0;
    rec.z = (int)((unsigned)wb[0] | ((unsigned)wb[1] << 16));
    rec.w = (int)((unsigned)wb[2] | ((unsigned)wb[3] << 16));
    esw[pos] = rec;
}

// ---- gather: 32 lanes/node, 4-edge groups, depth-2 pipeline ----
__global__ void gather_kernel(const int* __restrict__ excl, const int* __restrict__ deg,
                              const int4* __restrict__ esw,
                              const unsigned short* __restrict__ hb,
                              const float* __restrict__ b,
                              const int* __restrict__ ga,       // nullable
                              const float* __restrict__ other,  // nullable
                              float* __restrict__ out, int N) {
    const int node = blockIdx.x * 8 + (threadIdx.x >> 5);
    if (node >= N) return;
    const int j = threadIdx.x & 31;
    const int head = j >> 3;
    const int d = deg[node];
    const int start = excl[node];
    const unsigned short* hbj = hb + 4 * j;

    float4 acc = {0.f, 0.f, 0.f, 0.f};
    float wsum = 0.f;

    int4 rC[4], rN[4];
    ushort4 hC[4];
#pragma unroll
    for (int k = 0; k < 4; ++k) rC[k] = esw[start + k];
#pragma unroll
    for (int k = 0; k < 4; ++k)
        hC[k] = *(const ushort4*)(hbj + (size_t)rC[k].x * HC);
#pragma unroll
    for (int k = 0; k < 4; ++k) rN[k] = esw[start + 4 + k];

    for (int e = 0; e < d; e += 4) {
#pragma unroll
        for (int k = 0; k < 4; ++k) {
            unsigned int pk = (head < 2) ? (unsigned)rC[k].z : (unsigned)rC[k].w;
            unsigned short wu = (head & 1) ? (unsigned short)(pk >> 16)
                                           : (unsigned short)(pk & 0xffff);
            float w = (e + k < d) ? b2f(wu) : 0.f;
            acc.x += w * b2f(hC[k].x);
            acc.y += w * b2f(hC[k].y);
            acc.z += w * b2f(hC[k].z);
            acc.w += w * b2f(hC[k].w);
            wsum += w;
        }
#pragma unroll
        for (int k = 0; k < 4; ++k) rC[k] = rN[k];
#pragma unroll
        for (int k = 0; k < 4; ++k)
            hC[k] = *(const ushort4*)(hbj + (size_t)rC[k].x * HC);
#pragma unroll
        for (int k = 0; k < 4; ++k) rN[k] = esw[start + e + 8 + k];
    }

    const float inv = 1.f / wsum;
    const float4 bb = *(const float4*)(b + 4 * j);
    float4 o = {acc.x * inv + bb.x, acc.y * inv + bb.y,
                acc.z * inv + bb.z, acc.w * inv + bb.w};
    if (ga) {
        const float4 ov = *(const float4*)(other + (size_t)ga[node] * HC + 4 * j);
        o.x += ov.x; o.y += ov.y; o.z += ov.z; o.w += ov.w;
    }
    *(float4*)(out + (size_t)node * HC + 4 * j) = o;
}

extern "C" void kernel_launch(void* const* d_in, const int* in_sizes, int n_in,
                              void* d_out, int out_size, void* d_ws, size_t ws_size,
                              hipStream_t stream) {
    const float* x1  = (const float*)d_in[0];
    const int*   ei1 = (const int*)d_in[1];
    const float* x2  = (const float*)d_in[2];
    const int*   ei2 = (const int*)d_in[3];
    const int*   ga  = (const int*)d_in[4];
    const float* W1    = (const float*)d_in[5];
    const float* attS1 = (const float*)d_in[6];
    const float* attD1 = (const float*)d_in[7];
    const float* b1    = (const float*)d_in[8];
    const float* W2    = (const float*)d_in[9];
    const float* attS2 = (const float*)d_in[10];
    const float* attD2 = (const float*)d_in[11];
    const float* b2    = (const float*)d_in[12];

    const int N1 = in_sizes[0] / IN_DIM;
    const int E1 = in_sizes[1] / 2;
    const int N2 = in_sizes[2] / IN_DIM;
    const int E2 = in_sizes[3] / 2;
    const int S1 = E1 + N1, S2 = E2 + N2;

    // ---- workspace layout ----
    char* p = (char*)d_ws;
    auto alloc = [&](size_t bytes) {
        char* r = p; p += (bytes + 511) & ~(size_t)511; return r;
    };
    unsigned short* hb1 = (unsigned short*)alloc((size_t)N1 * HC * 2);
    unsigned short* hb2 = (unsigned short*)alloc((size_t)N2 * HC * 2);
    unsigned short* Wt1 = (unsigned short*)alloc((size_t)IN_DIM * HC * 2);
    unsigned short* Wt2 = (unsigned short*)alloc((size_t)IN_DIM * HC * 2);
    float* asrc1 = (float*)alloc((size_t)N1 * HH * 4);
    float* adst1 = (float*)alloc((size_t)N1 * HH * 4);
    float* asrc2 = (float*)alloc((size_t)N2 * HH * 4);
    float* adst2 = (float*)alloc((size_t)N2 * HH * 4);
    int* deg1 = (int*)alloc((size_t)(N1 + N2) * 4);   // deg1|deg2 -> one memset
    int* deg2 = deg1 + N1;
    int* incl1 = (int*)alloc((size_t)N1 * 4);
    int* incl2 = (int*)alloc((size_t)N2 * 4);
    int* excl1 = (int*)alloc((size_t)N1 * 4);
    int* excl2 = (int*)alloc((size_t)N2 * 4);
    int* bsum1 = (int*)alloc(256 * 4);
    int* bsum2 = (int*)alloc(256 * 4);
    int* rank  = (int*)alloc((size_t)(S1 + S2) * 4);
    int4* esw1 = (int4*)alloc((size_t)(S1 + 16) * 16);
    int4* esw2 = (int4*)alloc((size_t)(S2 + 16) * 16);

    float* out1 = (float*)d_out;
    float* out2 = (float*)d_out + (size_t)N1 * HC;

    hipMemsetAsync(deg1, 0, (size_t)(N1 + N2) * 4, stream);
    hipMemsetAsync(esw1 + S1, 0, 16 * 16, stream);   // zero prefetch pad
    hipMemsetAsync(esw2 + S2, 0, 16 * 16, stream);

    prep_kernel<<<2, 256, 0, stream>>>(W1, W2, Wt1, Wt2);

    // MEGA1: gemm1 | gemm2 | degree_rank overlapped (disjoint resources:
    // MFMA+HBM-reads vs memory-side atomic unit)
    const int G1 = (N1 + 127) / 128, G2 = (N2 + 127) / 128;
    const int GD = (S1 + S2 + 1023) / 1024;
    mega1_kernel<<<G1 + G2 + GD, 256, 0, stream>>>(
        x1, Wt1, attS1, attD1, hb1, asrc1, adst1, N1,
        x2, Wt2, attS2, attD2, hb2, asrc2, adst2, N2,
        ei1, E1, S1, ei2, E2, S2, deg1, deg2, rank, G1, G2);

    const int nb1 = (N1 + 255) / 256, nb2 = (N2 + 255) / 256;  // 196, 40
    scan_block_kernel<<<nb1 + nb2, 256, 0, stream>>>(deg1, incl1, bsum1, N1, nb1,
                                                     deg2, incl2, bsum2, N2);
    scan_top_kernel<<<2, 256, 0, stream>>>(bsum1, nb1, bsum2, nb2);
    add_off_kernel<<<nb1 + nb2, 256, 0, stream>>>(incl1, bsum1, deg1, excl1, N1, nb1,
                                                  incl2, bsum2, deg2, excl2, N2);

    scatter_kernel<<<(S1 + S2 + 255) / 256, 256, 0, stream>>>(
        ei1, E1, S1, ei2, E2, S2, excl1, esw1, excl2, esw2, rank,
        asrc1, adst1, asrc2, adst2);

    // gather: graph2 first (graph1 reads out2 through ga)
    gather_kernel<<<(N2 + 7) / 8, 256, 0, stream>>>(excl2, deg2, esw2, hb2,
                                                    b2, nullptr, nullptr, out2, N2);
    gather_kernel<<<(N1 + 7) / 8, 256, 0, stream>>>(excl1, deg1, esw1, hb1,
                                                    b1, ga, out2, out1, N1);
}